// Round 14
// baseline (155.636 us; speedup 1.0000x reference)
//
#include <hip/hip_runtime.h>
#include <hip/hip_bf16.h>
#include <math.h>

#define SEQ 720
#define NCH 128
#define BATCH 128
#define BN 16384
#define DOM 72
#define PIN 30
#define POUT 30
#define FRQ 33
#define EMB 64
#define PER 24
#define KW 990
#define KP 1728
#define MT 768
#define PI_F 3.14159265358979323846f

typedef float2 cf;
__device__ __forceinline__ cf cmac(cf acc, cf a, cf b){
  acc.x += a.x*b.x - a.y*b.y; acc.y += a.x*b.y + a.y*b.x; return acc;
}
__device__ __forceinline__ short b2s(float f){
  __hip_bfloat16 h = __float2bfloat16(f);
  return *reinterpret_cast<short*>(&h);
}

// ---------------- P15: block 72 = p1 weight-composition; blocks 0..71 = p5 A1 rows ----------------
__global__ __launch_bounds__(256) void p15(const float* __restrict__ WPW, const float* __restrict__ WPb,
                         const float* __restrict__ m1r, const float* __restrict__ m1i,
                         const float* __restrict__ m1br, const float* __restrict__ m1bi,
                         const float* __restrict__ fxr, const float* __restrict__ fxi,
                         const float* __restrict__ fxbr, const float* __restrict__ fxbi,
                         const float* __restrict__ pjr, const float* __restrict__ pji,
                         const float* __restrict__ pjbr, const float* __restrict__ pjbi,
                         const float* __restrict__ fqr, const float* __restrict__ fqi,
                         cf* C, cf* PM, cf* M2, cf* o3b,
                         float* __restrict__ A1r, float* __restrict__ A1i)
{
  __shared__ cf e64[64];
  __shared__ float sW[EMB*PER];
  __shared__ float sWb[EMB];
  __shared__ float sM1r[PIN*PIN], sM1i[PIN*PIN];
  __shared__ float sFxr[FRQ*FRQ], sFxi[FRQ*FRQ];
  __shared__ float sPjr[POUT*PIN], sPji[POUT*PIN];
  __shared__ float sB[6*33];
  __shared__ cf s_d[FRQ];
  __shared__ cf s_rs[PIN];
  __shared__ cf s_o1[FRQ*PIN];
  __shared__ cf s_o2[FRQ*PIN];
  __shared__ cf tbl[720];
  __shared__ cf wrow[DOM];

  int tid = threadIdx.x;
  if (blockIdx.x < DOM){
    int k = blockIdx.x;
    for (int m=tid;m<720;m+=256){ float s,c; sincosf(-2.f*PI_F*(float)m/720.f,&s,&c); tbl[m]=make_float2(c,s); }
    for (int j=tid;j<DOM;j+=256) wrow[j]=make_float2(fqr[k*DOM+j], fqi[k*DOM+j]);
    __syncthreads();
    for (int tau=tid; tau<720; tau+=256){
      cf acc=make_float2(0.f,0.f);
      for (int j=0;j<DOM;++j) acc = cmac(acc, wrow[j], tbl[(j*tau)%720]);
      A1r[k*720+tau]=acc.x;
      A1i[k*720+tau]=acc.y;
    }
    return;
  }
  if (tid < 64){ float s,c; sincosf(2.f*PI_F*tid/64.f, &s, &c); e64[tid] = make_float2(c, s); }
  for (int i=tid; i<EMB*PER; i+=256) sW[i]=WPW[i];
  if (tid < EMB) sWb[tid]=WPb[tid];
  for (int i=tid; i<PIN*PIN; i+=256){ sM1r[i]=m1r[i]; sM1i[i]=m1i[i]; sPjr[i]=pjr[i]; sPji[i]=pji[i]; }
  for (int i=tid; i<FRQ*FRQ; i+=256){ sFxr[i]=fxr[i]; sFxi[i]=fxi[i]; }
  if (tid < PIN)  { sB[tid]      = m1br[tid]; sB[33+tid]  = m1bi[tid]; }
  if (tid < FRQ)  { sB[66+tid]   = fxbr[tid]; sB[99+tid]  = fxbi[tid]; }
  if (tid < POUT) { sB[132+tid]  = pjbr[tid]; sB[165+tid] = pjbi[tid]; }
  __syncthreads();
  for (int idx=tid; idx<FRQ*PER; idx+=256){
    int f = idx/PER, i = idx%PER;
    cf acc = make_float2(0.f,0.f);
    #pragma unroll 8
    for (int o=0;o<EMB;++o){ cf e = e64[(f*o)&63]; float w = sW[o*PER+i]; acc.x += w*e.x; acc.y -= w*e.y; }
    C[idx] = acc;
  }
  for (int f=tid; f<FRQ; f+=256){
    cf acc = make_float2(0.f,0.f);
    #pragma unroll 8
    for (int o=0;o<EMB;++o){ cf e = e64[(f*o)&63]; acc.x += sWb[o]*e.x; acc.y -= sWb[o]*e.y; }
    s_d[f]=acc;
  }
  for (int idx=tid; idx<POUT*PIN; idx+=256){
    int q = idx/PIN, pp = idx%PIN;
    cf acc = make_float2(sPjr[q*PIN+pp], sPji[q*PIN+pp]);
    #pragma unroll 6
    for (int p=0;p<PIN;++p){
      cf a = make_float2(sPjr[q*PIN+p], sPji[q*PIN+p]);
      cf b = make_float2(sM1r[p*PIN+pp], sM1i[p*PIN+pp]);
      acc = cmac(acc, a, b);
    }
    PM[idx]=acc;
  }
  for (int idx=tid; idx<FRQ*FRQ; idx+=256){
    int f = idx/FRQ, ff = idx%FRQ;
    cf v = make_float2(sFxr[idx], sFxi[idx]); if (f==ff) v.x += 1.f;
    M2[idx]=v;
  }
  for (int p=tid; p<PIN; p+=256){
    cf acc = make_float2(1.f,0.f);
    #pragma unroll 6
    for (int pp=0;pp<PIN;++pp){ acc.x += sM1r[p*PIN+pp]; acc.y += sM1i[p*PIN+pp]; }
    s_rs[p]=acc;
  }
  __syncthreads();
  for (int idx=tid; idx<FRQ*PIN; idx+=256){
    int f = idx/PIN, p = idx%PIN;
    cf v = make_float2(0.f,0.f); v = cmac(v, s_d[f], s_rs[p]);
    v.x += sB[p]; v.y += sB[33+p];
    s_o1[idx]=v;
  }
  __syncthreads();
  for (int idx=tid; idx<FRQ*PIN; idx+=256){
    int f = idx/PIN, p = idx%PIN;
    cf acc = make_float2(sB[66+f], sB[99+f]);
    #pragma unroll 4
    for (int ff=0; ff<FRQ; ++ff){
      cf m2 = make_float2(sFxr[f*FRQ+ff], sFxi[f*FRQ+ff]); if (f==ff) m2.x += 1.f;
      acc = cmac(acc, m2, s_o1[ff*PIN+p]);
    }
    s_o2[idx]=acc;
  }
  __syncthreads();
  for (int idx=tid; idx<FRQ*POUT; idx+=256){
    int f = idx/POUT, q = idx%POUT;
    cf acc = make_float2(sB[132+q], sB[165+q]);
    #pragma unroll 6
    for (int p=0;p<PIN;++p){
      cf a = make_float2(sPjr[q*PIN+p], sPji[q*PIN+p]);
      acc = cmac(acc, a, s_o2[f*PIN+p]);
    }
    o3b[f*POUT+q]=acc;
  }
}

// ---------------- FUSED_MID (512 threads): blocks [0,720)=p_big3 (incl. Mlow join);
//                  [720,3792)=x transpose; [3792,5840)=Wpos repack ----------------
__global__ __launch_bounds__(512) void fused_mid(const float* __restrict__ hW,
                    const cf* __restrict__ PM, const cf* __restrict__ M2, const cf* __restrict__ o3b,
                    const cf* __restrict__ Cm,
                    const float* __restrict__ fbr, const float* __restrict__ fbi,
                    const float* __restrict__ headb,
                    const float* __restrict__ A1r, const float* __restrict__ A1i,
                    const float* __restrict__ x, const float* __restrict__ Wp,
                    __hip_bfloat16* __restrict__ BTm, float* __restrict__ bias,
                    __hip_bfloat16* __restrict__ Abig){
  __shared__ double smem_d[6336];   // 50688 B arena, manually unioned
  char* smem = (char*)smem_d;
  int tid = threadIdx.x;
  int blk = blockIdx.x;

  if (blk < SEQ){
    // ---------- p_big3 ----------
    cf*    e64 = (cf*)(smem + 0);        // 64 cf   = 512
    float* shw = (float*)(smem + 512);   // 1920 f  = 7680
    cf*    sHc = (cf*)(smem + 8192);     // 990 cf  = 7920
    cf*    sV1 = (cf*)(smem + 16112);    // 990 cf  = 7920
    cf*    sPM = (cf*)(smem + 24032);    // 900 cf  = 7200
    cf*    sM2 = (cf*)(smem + 31232);    // 1089 cf = 8712
    cf*    sO3 = (cf*)(smem + 39944);    // 990 cf  = 7920
    float* red = (float*)(smem + 47864); // 512 f   = 2048
    float* sG  = (float*)(smem + 49912); // 144 f   = 576  (Gr[0..71], Gi[72..143])
    cf* sC = (cf*)shw;                   // aliases shw after phase A
    cf* sV = sHc;                        // aliases sHc after phase B
    int t = blk;
    if (tid<64){ float s,c; sincosf(2.f*PI_F*tid/64.f,&s,&c); e64[tid]=make_float2(c,s); }
    if (tid<DOM){
      int m=(tid*t)%720; float s,c; sincosf(2.f*PI_F*(float)m/720.f,&s,&c);
      float sc=(tid==0)?(1.f/720.f):(2.f/720.f);
      sG[tid]=c*sc; sG[72+tid]=s*sc;
    }
    for (int i=tid;i<1920;i+=512) shw[i]=hW[(size_t)t*1920+i];
    for (int i=tid;i<POUT*PIN;i+=512) sPM[i]=PM[i];
    for (int i=tid;i<FRQ*FRQ;i+=512) sM2[i]=M2[i];
    for (int i=tid;i<FRQ*POUT;i+=512) sO3[i]=o3b[i];
    __syncthreads();
    // A: Hc[q][f]
    for (int idx=tid; idx<990; idx+=512){
      int q=idx/FRQ, f=idx%FRQ;
      cf acc=make_float2(0.f,0.f);
      const float* hw = &shw[q*64];
      #pragma unroll 8
      for (int o=0;o<EMB;++o){ cf e=e64[(f*o)&63]; float w=hw[o]; acc.x+=w*e.x; acc.y+=w*e.y; }
      float s=((f==0)||(f==32))?(1.f/64.f):(2.f/64.f);
      sHc[idx]=make_float2(acc.x*s, acc.y*s);
    }
    __syncthreads();   // shw consumed; sHc ready
    // B: V1 ; bias partial ; load sC (overwrites shw)
    for (int idx=tid; idx<990; idx+=512){
      int f=idx/PIN, p=idx%PIN;
      cf acc=make_float2(0.f,0.f);
      #pragma unroll 6
      for (int q=0;q<POUT;++q) acc=cmac(acc, sHc[q*FRQ+f], sPM[q*PIN+p]);
      sV1[idx]=acc;
    }
    float part=0.f;
    for (int idx=tid; idx<990; idx+=512){
      int q=idx/FRQ, f=idx%FRQ;
      cf h=sHc[idx]; cf o=sO3[f*POUT+q];
      part += h.x*o.x - h.y*o.y;
    }
    part *= 0.7f;
    if (tid<DOM){
      int m=(tid*t)%720; float s,c; sincosf(2.f*PI_F*(float)m/720.f,&s,&c);
      float sc=(tid==0)?(1.f/720.f):(2.f/720.f);
      part += 0.3f*sc*(c*fbr[tid] - s*fbi[tid]);
    }
    for (int i=tid;i<FRQ*PER;i+=512) sC[i]=Cm[i];
    red[tid]=part; __syncthreads();
    for (int s=256;s>0;s>>=1){ if (tid<s) red[tid]+=red[tid+s]; __syncthreads(); }
    if (tid==0) bias[t] = red[0] + 0.7f*headb[t];
    __syncthreads();   // sHc reads done; sC loaded
    // D: V[ff][pp] -> sV
    for (int idx=tid; idx<990; idx+=512){
      int ff=idx/PIN, pp=idx%PIN;
      cf acc=make_float2(0.f,0.f);
      #pragma unroll 4
      for (int f=0;f<FRQ;++f) acc=cmac(acc, sV1[f*PIN+pp], sM2[f*FRQ+ff]);
      sV[idx]=acc;
    }
    __syncthreads();
    // E: mper + Mlow join -> BTm[:,0:720] ; Wpos columns -> BTm[:,720:1728)
    for (int tau=tid; tau<720; tau+=512){
      int p0 = tau/PER, i0 = tau - p0*PER;
      float mper=0.f;
      #pragma unroll 4
      for (int f=0; f<FRQ; ++f){ cf v=sV[f*PIN+p0]; cf c=sC[f*PER+i0]; mper += v.x*c.x - v.y*c.y; }
      float mlow=0.f;
      #pragma unroll 8
      for (int k=0;k<DOM;++k)
        mlow += sG[k]*A1r[k*720+tau] - sG[72+k]*A1i[k*720+tau];
      BTm[(size_t)t*KP + tau] = __float2bfloat16(0.3f*mlow + 0.7f*mper);
    }
    for (int j=tid;j<KP-SEQ;j+=512){
      float v = 0.f;
      if (j < KW){ int p=j/FRQ, f=j-p*FRQ; v = 0.7f * sV[f*PIN+p].x; }
      BTm[(size_t)t*KP + SEQ + j] = __float2bfloat16(v);
    }
    return;
  }

  if (blk < SEQ + 3072){
    // ---------- x transpose: one 64x64 tile, 512 threads ----------
    float (*tile)[65] = (float(*)[65])smem;
    int bb = blk - SEQ;
    int b = bb/24; int rem = bb%24;
    int t0 = (rem>>1)*64, n0 = (rem&1)*64;
    int c = tid & 63, r0 = tid >> 6;   // r0 0..7
    #pragma unroll
    for (int s=0;s<8;++s){
      int r = r0 + s*8;
      int t = t0 + r;
      tile[r][c] = (t<SEQ) ? x[((size_t)b*SEQ + t)*NCH + n0 + c] : 0.f;
    }
    __syncthreads();
    int tq  = tid & 15;        // t-quad
    int nn0 = tid >> 4;        // 0..31
    int tt  = t0 + tq*4;
    #pragma unroll
    for (int s=0;s<2;++s){
      int nn = nn0 + s*32;
      short4 v;
      v.x = b2s(tile[tq*4+0][nn]);
      v.y = b2s(tile[tq*4+1][nn]);
      v.z = b2s(tile[tq*4+2][nn]);
      v.w = b2s(tile[tq*4+3][nn]);
      __hip_bfloat16* dst = Abig + (size_t)(b*NCH + n0+nn)*KP + tt;
      if (tt+3 < SEQ){
        *reinterpret_cast<short4*>(dst) = v;
      } else {
        short sv[4] = {v.x, v.y, v.z, v.w};
        for (int j=0;j<4;++j) if (tt+j < SEQ) *reinterpret_cast<short*>(dst+j) = sv[j];
      }
    }
    return;
  }

  // ---------- Wpos repack: 8 bn per block ----------
  {
    int bb = blk - SEQ - 3072;
    int lane8 = tid >> 6;          // 0..7
    int bn = bb*8 + lane8;
    int j = (tid & 63)*4;
    const float* src = Wp + (size_t)bn*KW;
    __hip_bfloat16* dstb = Abig + (size_t)bn*KP + SEQ;
    for (int jj = j; jj < KP-SEQ; jj += 256){
      float f0,f1,f2,f3;
      if (jj+3 < KW){
        float2 u = *reinterpret_cast<const float2*>(src+jj);
        float2 w = *reinterpret_cast<const float2*>(src+jj+2);
        f0=u.x; f1=u.y; f2=w.x; f3=w.y;
      } else {
        f0=(jj  <KW)?src[jj  ]:0.f; f1=(jj+1<KW)?src[jj+1]:0.f;
        f2=(jj+2<KW)?src[jj+2]:0.f; f3=(jj+3<KW)?src[jj+3]:0.f;
      }
      short4 v = { b2s(f0), b2s(f1), b2s(f2), b2s(f3) };
      *reinterpret_cast<short4*>(dstb + jj) = v;
    }
  }
}

// ---------------- GEMM (2-phase double-buffer: stage(k+1) overlaps MFMA(k), ONE barrier/step) ----------------
typedef __attribute__((ext_vector_type(8))) short bfrag_t;
typedef __attribute__((ext_vector_type(4))) float accf_t;
typedef __attribute__((address_space(1))) void gvoid;
typedef __attribute__((address_space(3))) void lvoid;

__device__ __forceinline__ void gload16(const void* g, void* l){
  __builtin_amdgcn_global_load_lds((gvoid*)(g), (lvoid*)(l), 16, 0, 0);
}

__global__ __launch_bounds__(256) void gemm_main(const __hip_bfloat16* __restrict__ BTm,
                                                 const __hip_bfloat16* __restrict__ Abig,
                                                 const float* __restrict__ bias,
                                                 float* __restrict__ out)
{
  __shared__ __hip_bfloat16 Abuf[2][128*32];
  __shared__ __hip_bfloat16 Bbuf[2][128*32];
  int tid = threadIdx.x;
  int lane = tid & 63;
  int wv = tid >> 6;
  int wr = wv >> 1, wc = wv & 1;
  int t0 = blockIdx.y*128, bn0 = blockIdx.x*128;

  accf_t acc[4][4];
  #pragma unroll
  for (int i=0;i<4;++i)
    #pragma unroll
    for (int j=0;j<4;++j) acc[i][j] = (accf_t){0.f,0.f,0.f,0.f};

  int lin0 = tid, lin1 = 256+tid;
  int row0 = lin0>>2, ug0 = (lin0&3) ^ ((row0>>1)&3);
  int row1 = lin1>>2, ug1 = (lin1&3) ^ ((row1>>1)&3);
  const __hip_bfloat16* gA0 = BTm  + (size_t)(t0 +row0)*KP + ug0*8;
  const __hip_bfloat16* gA1 = BTm  + (size_t)(t0 +row1)*KP + ug1*8;
  const __hip_bfloat16* gB0 = Abig + (size_t)(bn0+row0)*KP + ug0*8;
  const __hip_bfloat16* gB1 = Abig + (size_t)(bn0+row1)*KP + ug1*8;
  int off0 = lin0*16, off1 = lin1*16;

  int g = lane>>4;
  int arow = wr*64 + (lane&15);
  int brow = wc*64 + (lane&15);

  // prologue: stage tile 0 into buf 0
  gload16(gA0, (char*)Abuf[0] + off0);
  gload16(gA1, (char*)Abuf[0] + off1);
  gload16(gB0, (char*)Bbuf[0] + off0);
  gload16(gB1, (char*)Bbuf[0] + off1);
  __syncthreads();

  int cur = 0;
  for (int ks=0; ks<KP/32 - 1; ++ks){
    int kn = (ks+1)*32;
    // issue next-tile stage FIRST -> flies during MFMA below
    char* an = (char*)Abuf[cur^1];
    char* bn_ = (char*)Bbuf[cur^1];
    gload16(gA0 + kn, an + off0);
    gload16(gA1 + kn, an + off1);
    gload16(gB0 + kn, bn_ + off0);
    gload16(gB1 + kn, bn_ + off1);
    // compute current tile
    const char* Ab = (const char*)Abuf[cur];
    const char* Bb = (const char*)Bbuf[cur];
    bfrag_t af[4], bb[4];
    #pragma unroll
    for (int mi=0;mi<4;++mi){
      int r = arow + mi*16;
      int uu = g ^ ((r>>1)&3);
      af[mi] = *(const bfrag_t*)(Ab + r*64 + uu*16);
    }
    #pragma unroll
    for (int ni=0;ni<4;++ni){
      int r = brow + ni*16;
      int uu = g ^ ((r>>1)&3);
      bb[ni] = *(const bfrag_t*)(Bb + r*64 + uu*16);
    }
    #pragma unroll
    for (int mi=0;mi<4;++mi)
      #pragma unroll
      for (int ni=0;ni<4;++ni)
        acc[mi][ni] = __builtin_amdgcn_mfma_f32_16x16x32_bf16(af[mi], bb[ni], acc[mi][ni], 0, 0, 0);
    __syncthreads();   // single drain: vmcnt(0)+lgkmcnt(0)+barrier -> next buf published
    cur ^= 1;
  }
  // final tile (no prefetch)
  {
    const char* Ab = (const char*)Abuf[cur];
    const char* Bb = (const char*)Bbuf[cur];
    bfrag_t af[4], bb[4];
    #pragma unroll
    for (int mi=0;mi<4;++mi){
      int r = arow + mi*16;
      int uu = g ^ ((r>>1)&3);
      af[mi] = *(const bfrag_t*)(Ab + r*64 + uu*16);
    }
    #pragma unroll
    for (int ni=0;ni<4;++ni){
      int r = brow + ni*16;
      int uu = g ^ ((r>>1)&3);
      bb[ni] = *(const bfrag_t*)(Bb + r*64 + uu*16);
    }
    #pragma unroll
    for (int mi=0;mi<4;++mi)
      #pragma unroll
      for (int ni=0;ni<4;++ni)
        acc[mi][ni] = __builtin_amdgcn_mfma_f32_16x16x32_bf16(af[mi], bb[ni], acc[mi][ni], 0, 0, 0);
  }

  #pragma unroll
  for (int mi=0;mi<4;++mi){
    int tbase = t0 + wr*64 + mi*16 + (lane>>4)*4;
    #pragma unroll
    for (int ni=0;ni<4;++ni){
      int col = bn0 + wc*64 + ni*16 + (lane&15);
      int b = col>>7, n = col&127;
      size_t obase = (size_t)b*(SEQ*NCH) + n;
      #pragma unroll
      for (int r=0;r<4;++r){
        int t = tbase + r;
        if (t<SEQ) out[obase + (size_t)t*NCH] = acc[mi][ni][r] + bias[t];
      }
    }
  }
}

extern "C" void kernel_launch(void* const* d_in, const int* in_sizes, int n_in,
                              void* d_out, int out_size, void* d_ws, size_t ws_size,
                              hipStream_t stream)
{
  const float* x     = (const float*)d_in[0];
  const float* fqWr  = (const float*)d_in[1];
  const float* fqWi  = (const float*)d_in[2];
  const float* fqbr  = (const float*)d_in[3];
  const float* fqbi  = (const float*)d_in[4];
  const float* WPW   = (const float*)d_in[5];
  const float* WPb   = (const float*)d_in[6];
  const float* Wpos  = (const float*)d_in[7];
  const float* m1r   = (const float*)d_in[8];
  const float* m1i   = (const float*)d_in[9];
  const float* m1br  = (const float*)d_in[10];
  const float* m1bi  = (const float*)d_in[11];
  const float* fxr   = (const float*)d_in[12];
  const float* fxi   = (const float*)d_in[13];
  const float* fxbr  = (const float*)d_in[14];
  const float* fxbi  = (const float*)d_in[15];
  const float* pjr   = (const float*)d_in[16];
  const float* pji   = (const float*)d_in[17];
  const float* pjbr  = (const float*)d_in[18];
  const float* pjbi  = (const float*)d_in[19];
  const float* headW = (const float*)d_in[20];
  const float* headb = (const float*)d_in[21];

  char* ws = (char*)d_ws;
  size_t off = 0;
  auto alloc = [&](size_t bytes)->void*{ void* p = ws + off; off += (bytes + 255) & ~(size_t)255; return p; };
  __hip_bfloat16* Abig = (__hip_bfloat16*)alloc((size_t)BN*KP*2);
  __hip_bfloat16* BTm  = (__hip_bfloat16*)alloc((size_t)MT*KP*2);
  float* A1r = (float*)alloc((size_t)DOM*720*4);
  float* A1i = (float*)alloc((size_t)DOM*720*4);
  cf* C   = (cf*)alloc((size_t)FRQ*PER*8);
  cf* PM  = (cf*)alloc((size_t)POUT*PIN*8);
  cf* M2  = (cf*)alloc((size_t)FRQ*FRQ*8);
  cf* o3b = (cf*)alloc((size_t)FRQ*POUT*8);
  float* bias = (float*)alloc((size_t)SEQ*4);

  p15<<<DOM+1,256,0,stream>>>(WPW,WPb, m1r,m1i,m1br,m1bi, fxr,fxi,fxbr,fxbi, pjr,pji,pjbr,pjbi,
                              fqWr,fqWi, C,PM,M2,o3b, A1r,A1i);
  fused_mid<<<SEQ+3072+2048,512,0,stream>>>(headW, PM, M2, o3b, C, fqbr, fqbi, headb,
                                            A1r, A1i, x, Wpos, BTm, bias, Abig);
  gemm_main<<<dim3(128, 6), 256, 0, stream>>>(BTm, Abig, bias, (float*)d_out);
}

// Round 15
// 128.621 us; speedup vs baseline: 1.2100x; 1.2100x over previous
//
#include <hip/hip_runtime.h>
#include <hip/hip_bf16.h>
#include <math.h>

#define SEQ 720
#define NCH 128
#define BATCH 128
#define BN 16384
#define DOM 72
#define PIN 30
#define POUT 30
#define FRQ 33
#define EMB 64
#define PER 24
#define KW 990
#define KP 1728
#define MT 768
#define PI_F 3.14159265358979323846f

typedef float2 cf;
typedef __attribute__((ext_vector_type(8))) short short8v;
__device__ __forceinline__ cf cmac(cf acc, cf a, cf b){
  acc.x += a.x*b.x - a.y*b.y; acc.y += a.x*b.y + a.y*b.x; return acc;
}
__device__ __forceinline__ short b2s(float f){
  __hip_bfloat16 h = __float2bfloat16(f);
  return *reinterpret_cast<short*>(&h);
}

// ---------------- FUSED_PRE (512 thr): blk[0,72)=A1 rows ; blk 72=p1 ; blk[73,3145)=x transpose
//                  (float4 load / short8 store) ; blk[3145,5193)=Wpos repack ----------------
__global__ __launch_bounds__(512) void fused_pre(
                         const float* __restrict__ WPW, const float* __restrict__ WPb,
                         const float* __restrict__ m1r, const float* __restrict__ m1i,
                         const float* __restrict__ m1br, const float* __restrict__ m1bi,
                         const float* __restrict__ fxr, const float* __restrict__ fxi,
                         const float* __restrict__ fxbr, const float* __restrict__ fxbi,
                         const float* __restrict__ pjr, const float* __restrict__ pji,
                         const float* __restrict__ pjbr, const float* __restrict__ pjbi,
                         const float* __restrict__ fqr, const float* __restrict__ fqi,
                         const float* __restrict__ x, const float* __restrict__ Wp,
                         cf* C, cf* PM, cf* M2, cf* o3b,
                         float* __restrict__ A1r, float* __restrict__ A1i,
                         __hip_bfloat16* __restrict__ Abig)
{
  __shared__ double arena_d[5900];   // 47200 B
  char* smem = (char*)arena_d;
  int tid = threadIdx.x;
  int blk = blockIdx.x;

  if (blk < DOM){
    // ---- A1[k][tau] ----
    cf* tbl  = (cf*)(smem);          // 720 cf
    cf* wrow = (cf*)(smem + 5760);   // 72 cf
    int k = blk;
    for (int m=tid;m<720;m+=512){ float s,c; sincosf(-2.f*PI_F*(float)m/720.f,&s,&c); tbl[m]=make_float2(c,s); }
    for (int j=tid;j<DOM;j+=512) wrow[j]=make_float2(fqr[k*DOM+j], fqi[k*DOM+j]);
    __syncthreads();
    for (int tau=tid; tau<720; tau+=512){
      cf acc=make_float2(0.f,0.f);
      for (int j=0;j<DOM;++j) acc = cmac(acc, wrow[j], tbl[(j*tau)%720]);
      A1r[k*720+tau]=acc.x;
      A1i[k*720+tau]=acc.y;
    }
    return;
  }

  if (blk == DOM){
    // ---- p1 weight composition ----
    cf*    e64  = (cf*)(smem + 0);
    float* sW   = (float*)(smem + 512);
    float* sWb  = (float*)(smem + 6656);
    float* sM1r = (float*)(smem + 6912);
    float* sM1i = (float*)(smem + 10512);
    float* sFxr = (float*)(smem + 14112);
    float* sFxi = (float*)(smem + 18468);
    float* sPjr = (float*)(smem + 22824);
    float* sPji = (float*)(smem + 26424);
    float* sB   = (float*)(smem + 30024);
    cf*    s_d  = (cf*)(smem + 30816);
    cf*    s_rs = (cf*)(smem + 31080);
    cf*    s_o1 = (cf*)(smem + 31320);
    cf*    s_o2 = (cf*)(smem + 39240);
    if (tid < 64){ float s,c; sincosf(2.f*PI_F*tid/64.f, &s, &c); e64[tid] = make_float2(c, s); }
    for (int i=tid; i<EMB*PER; i+=512) sW[i]=WPW[i];
    if (tid < EMB) sWb[tid]=WPb[tid];
    for (int i=tid; i<PIN*PIN; i+=512){ sM1r[i]=m1r[i]; sM1i[i]=m1i[i]; sPjr[i]=pjr[i]; sPji[i]=pji[i]; }
    for (int i=tid; i<FRQ*FRQ; i+=512){ sFxr[i]=fxr[i]; sFxi[i]=fxi[i]; }
    if (tid < PIN)  { sB[tid]      = m1br[tid]; sB[33+tid]  = m1bi[tid]; }
    if (tid < FRQ)  { sB[66+tid]   = fxbr[tid]; sB[99+tid]  = fxbi[tid]; }
    if (tid < POUT) { sB[132+tid]  = pjbr[tid]; sB[165+tid] = pjbi[tid]; }
    __syncthreads();
    for (int idx=tid; idx<FRQ*PER; idx+=512){
      int f = idx/PER, i = idx%PER;
      cf acc = make_float2(0.f,0.f);
      #pragma unroll 8
      for (int o=0;o<EMB;++o){ cf e = e64[(f*o)&63]; float w = sW[o*PER+i]; acc.x += w*e.x; acc.y -= w*e.y; }
      C[idx] = acc;
    }
    for (int f=tid; f<FRQ; f+=512){
      cf acc = make_float2(0.f,0.f);
      #pragma unroll 8
      for (int o=0;o<EMB;++o){ cf e = e64[(f*o)&63]; acc.x += sWb[o]*e.x; acc.y -= sWb[o]*e.y; }
      s_d[f]=acc;
    }
    for (int idx=tid; idx<POUT*PIN; idx+=512){
      int q = idx/PIN, pp = idx%PIN;
      cf acc = make_float2(sPjr[q*PIN+pp], sPji[q*PIN+pp]);
      #pragma unroll 6
      for (int p=0;p<PIN;++p){
        cf a = make_float2(sPjr[q*PIN+p], sPji[q*PIN+p]);
        cf b = make_float2(sM1r[p*PIN+pp], sM1i[p*PIN+pp]);
        acc = cmac(acc, a, b);
      }
      PM[idx]=acc;
    }
    for (int idx=tid; idx<FRQ*FRQ; idx+=512){
      int f = idx/FRQ, ff = idx%FRQ;
      cf v = make_float2(sFxr[idx], sFxi[idx]); if (f==ff) v.x += 1.f;
      M2[idx]=v;
    }
    for (int p=tid; p<PIN; p+=512){
      cf acc = make_float2(1.f,0.f);
      #pragma unroll 6
      for (int pp=0;pp<PIN;++pp){ acc.x += sM1r[p*PIN+pp]; acc.y += sM1i[p*PIN+pp]; }
      s_rs[p]=acc;
    }
    __syncthreads();
    for (int idx=tid; idx<FRQ*PIN; idx+=512){
      int f = idx/PIN, p = idx%PIN;
      cf v = make_float2(0.f,0.f); v = cmac(v, s_d[f], s_rs[p]);
      v.x += sB[p]; v.y += sB[33+p];
      s_o1[idx]=v;
    }
    __syncthreads();
    for (int idx=tid; idx<FRQ*PIN; idx+=512){
      int f = idx/PIN, p = idx%PIN;
      cf acc = make_float2(sB[66+f], sB[99+f]);
      #pragma unroll 4
      for (int ff=0; ff<FRQ; ++ff){
        cf m2 = make_float2(sFxr[f*FRQ+ff], sFxi[f*FRQ+ff]); if (f==ff) m2.x += 1.f;
        acc = cmac(acc, m2, s_o1[ff*PIN+p]);
      }
      s_o2[idx]=acc;
    }
    __syncthreads();
    for (int idx=tid; idx<FRQ*POUT; idx+=512){
      int f = idx/POUT, q = idx%POUT;
      cf acc = make_float2(sB[132+q], sB[165+q]);
      #pragma unroll 6
      for (int p=0;p<PIN;++p){
        cf a = make_float2(sPjr[q*PIN+p], sPji[q*PIN+p]);
        acc = cmac(acc, a, s_o2[f*PIN+p]);
      }
      o3b[f*POUT+q]=acc;
    }
    return;
  }

  if (blk < DOM + 1 + 3072){
    // ---- x transpose: 64x64 tile, float4 loads, short8 stores ----
    float (*tile)[68] = (float(*)[68])smem;   // 64*68*4 = 17408 B
    int bb = blk - (DOM+1);
    int b = bb/24; int rem = bb%24;
    int t0 = (rem>>1)*64, n0 = (rem&1)*64;
    int r0 = tid >> 4;            // 0..31
    int c4 = (tid & 15)*4;        // 0..60
    #pragma unroll
    for (int s=0;s<2;++s){
      int r = r0 + s*32;
      int t = t0 + r;
      float4 v = make_float4(0.f,0.f,0.f,0.f);
      if (t < SEQ) v = *reinterpret_cast<const float4*>(&x[((size_t)b*SEQ + t)*NCH + n0 + c4]);
      *reinterpret_cast<float4*>(&tile[r][c4]) = v;
    }
    __syncthreads();
    int n  = tid & 63;            // column
    int tg = tid >> 6;            // 0..7 t-group
    int tt = tg*8;
    if (t0 + tt < SEQ){           // 720%8==0 and t0%64==0 -> group fully valid or fully out
      short8v v;
      #pragma unroll
      for (int j=0;j<8;++j) v[j] = b2s(tile[tt+j][n]);
      *reinterpret_cast<short8v*>(Abig + (size_t)(b*NCH + n0+n)*KP + t0 + tt) = v;
    }
    return;
  }

  // ---- Wpos repack: 8 bn per block ----
  {
    int bb = blk - (DOM+1) - 3072;
    int lane8 = tid >> 6;          // 0..7
    int bn = bb*8 + lane8;
    int j = (tid & 63)*4;
    const float* src = Wp + (size_t)bn*KW;
    __hip_bfloat16* dstb = Abig + (size_t)bn*KP + SEQ;
    for (int jj = j; jj < KP-SEQ; jj += 256){
      float f0,f1,f2,f3;
      if (jj+3 < KW){
        float2 u = *reinterpret_cast<const float2*>(src+jj);
        float2 w = *reinterpret_cast<const float2*>(src+jj+2);
        f0=u.x; f1=u.y; f2=w.x; f3=w.y;
      } else {
        f0=(jj  <KW)?src[jj  ]:0.f; f1=(jj+1<KW)?src[jj+1]:0.f;
        f2=(jj+2<KW)?src[jj+2]:0.f; f3=(jj+3<KW)?src[jj+3]:0.f;
      }
      short4 v = { b2s(f0), b2s(f1), b2s(f2), b2s(f3) };
      *reinterpret_cast<short4*>(dstb + jj) = v;
    }
  }
}

// ---------------- P_BIG3 (512 thr, 720 blocks): p2+p3+p4+p7 + mper/Mlow join + Wpos cols ----------------
__global__ __launch_bounds__(512) void p_big3(const float* __restrict__ hW,
                    const cf* __restrict__ PM, const cf* __restrict__ M2, const cf* __restrict__ o3b,
                    const cf* __restrict__ Cm,
                    const float* __restrict__ fbr, const float* __restrict__ fbi,
                    const float* __restrict__ headb,
                    const float* __restrict__ A1r, const float* __restrict__ A1i,
                    __hip_bfloat16* __restrict__ BTm, float* __restrict__ bias){
  __shared__ double smem_d[6336];   // 50688 B arena
  char* smem = (char*)smem_d;
  int tid = threadIdx.x;
  cf*    e64 = (cf*)(smem + 0);
  float* shw = (float*)(smem + 512);
  cf*    sHc = (cf*)(smem + 8192);
  cf*    sV1 = (cf*)(smem + 16112);
  cf*    sPM = (cf*)(smem + 24032);
  cf*    sM2 = (cf*)(smem + 31232);
  cf*    sO3 = (cf*)(smem + 39944);
  float* red = (float*)(smem + 47864);
  float* sG  = (float*)(smem + 49912);
  cf* sC = (cf*)shw;
  cf* sV = sHc;
  int t = blockIdx.x;
  if (tid<64){ float s,c; sincosf(2.f*PI_F*tid/64.f,&s,&c); e64[tid]=make_float2(c,s); }
  if (tid<DOM){
    int m=(tid*t)%720; float s,c; sincosf(2.f*PI_F*(float)m/720.f,&s,&c);
    float sc=(tid==0)?(1.f/720.f):(2.f/720.f);
    sG[tid]=c*sc; sG[72+tid]=s*sc;
  }
  for (int i=tid;i<1920;i+=512) shw[i]=hW[(size_t)t*1920+i];
  for (int i=tid;i<POUT*PIN;i+=512) sPM[i]=PM[i];
  for (int i=tid;i<FRQ*FRQ;i+=512) sM2[i]=M2[i];
  for (int i=tid;i<FRQ*POUT;i+=512) sO3[i]=o3b[i];
  __syncthreads();
  for (int idx=tid; idx<990; idx+=512){
    int q=idx/FRQ, f=idx%FRQ;
    cf acc=make_float2(0.f,0.f);
    const float* hw = &shw[q*64];
    #pragma unroll 8
    for (int o=0;o<EMB;++o){ cf e=e64[(f*o)&63]; float w=hw[o]; acc.x+=w*e.x; acc.y+=w*e.y; }
    float s=((f==0)||(f==32))?(1.f/64.f):(2.f/64.f);
    sHc[idx]=make_float2(acc.x*s, acc.y*s);
  }
  __syncthreads();
  for (int idx=tid; idx<990; idx+=512){
    int f=idx/PIN, p=idx%PIN;
    cf acc=make_float2(0.f,0.f);
    #pragma unroll 6
    for (int q=0;q<POUT;++q) acc=cmac(acc, sHc[q*FRQ+f], sPM[q*PIN+p]);
    sV1[idx]=acc;
  }
  float part=0.f;
  for (int idx=tid; idx<990; idx+=512){
    int q=idx/FRQ, f=idx%FRQ;
    cf h=sHc[idx]; cf o=sO3[f*POUT+q];
    part += h.x*o.x - h.y*o.y;
  }
  part *= 0.7f;
  if (tid<DOM){
    int m=(tid*t)%720; float s,c; sincosf(2.f*PI_F*(float)m/720.f,&s,&c);
    float sc=(tid==0)?(1.f/720.f):(2.f/720.f);
    part += 0.3f*sc*(c*fbr[tid] - s*fbi[tid]);
  }
  for (int i=tid;i<FRQ*PER;i+=512) sC[i]=Cm[i];
  red[tid]=part; __syncthreads();
  for (int s=256;s>0;s>>=1){ if (tid<s) red[tid]+=red[tid+s]; __syncthreads(); }
  if (tid==0) bias[t] = red[0] + 0.7f*headb[t];
  __syncthreads();
  for (int idx=tid; idx<990; idx+=512){
    int ff=idx/PIN, pp=idx%PIN;
    cf acc=make_float2(0.f,0.f);
    #pragma unroll 4
    for (int f=0;f<FRQ;++f) acc=cmac(acc, sV1[f*PIN+pp], sM2[f*FRQ+ff]);
    sV[idx]=acc;
  }
  __syncthreads();
  for (int tau=tid; tau<720; tau+=512){
    int p0 = tau/PER, i0 = tau - p0*PER;
    float mper=0.f;
    #pragma unroll 4
    for (int f=0; f<FRQ; ++f){ cf v=sV[f*PIN+p0]; cf c=sC[f*PER+i0]; mper += v.x*c.x - v.y*c.y; }
    float mlow=0.f;
    #pragma unroll 8
    for (int k=0;k<DOM;++k)
      mlow += sG[k]*A1r[k*720+tau] - sG[72+k]*A1i[k*720+tau];
    BTm[(size_t)t*KP + tau] = __float2bfloat16(0.3f*mlow + 0.7f*mper);
  }
  for (int j=tid;j<KP-SEQ;j+=512){
    float v = 0.f;
    if (j < KW){ int p=j/FRQ, f=j-p*FRQ; v = 0.7f * sV[f*PIN+p].x; }
    BTm[(size_t)t*KP + SEQ + j] = __float2bfloat16(v);
  }
}

// ---------------- GEMM (round-13 proven: 1-phase, BK=32, natural mapping) ----------------
typedef __attribute__((ext_vector_type(8))) short bfrag_t;
typedef __attribute__((ext_vector_type(4))) float accf_t;
typedef __attribute__((address_space(1))) void gvoid;
typedef __attribute__((address_space(3))) void lvoid;

__device__ __forceinline__ void gload16(const void* g, void* l){
  __builtin_amdgcn_global_load_lds((gvoid*)(g), (lvoid*)(l), 16, 0, 0);
}

__global__ __launch_bounds__(256) void gemm_main(const __hip_bfloat16* __restrict__ BTm,
                                                 const __hip_bfloat16* __restrict__ Abig,
                                                 const float* __restrict__ bias,
                                                 float* __restrict__ out)
{
  __shared__ __hip_bfloat16 At[128*32];
  __shared__ __hip_bfloat16 Bt[128*32];
  int tid = threadIdx.x;
  int lane = tid & 63;
  int wv = tid >> 6;
  int wr = wv >> 1, wc = wv & 1;
  int t0 = blockIdx.y*128, bn0 = blockIdx.x*128;

  accf_t acc[4][4];
  #pragma unroll
  for (int i=0;i<4;++i)
    #pragma unroll
    for (int j=0;j<4;++j) acc[i][j] = (accf_t){0.f,0.f,0.f,0.f};

  int lin0 = tid, lin1 = 256+tid;
  int row0 = lin0>>2, ug0 = (lin0&3) ^ ((row0>>1)&3);
  int row1 = lin1>>2, ug1 = (lin1&3) ^ ((row1>>1)&3);
  const __hip_bfloat16* gA0 = BTm  + (size_t)(t0 +row0)*KP + ug0*8;
  const __hip_bfloat16* gA1 = BTm  + (size_t)(t0 +row1)*KP + ug1*8;
  const __hip_bfloat16* gB0 = Abig + (size_t)(bn0+row0)*KP + ug0*8;
  const __hip_bfloat16* gB1 = Abig + (size_t)(bn0+row1)*KP + ug1*8;
  char* lA0 = (char*)At + lin0*16; char* lA1 = (char*)At + lin1*16;
  char* lB0 = (char*)Bt + lin0*16; char* lB1 = (char*)Bt + lin1*16;

  int g = lane>>4;
  int arow = wr*64 + (lane&15);
  int brow = wc*64 + (lane&15);

  for (int ks=0; ks<KP/32; ++ks){
    int k0 = ks*32;
    gload16(gA0 + k0, lA0);
    gload16(gA1 + k0, lA1);
    gload16(gB0 + k0, lB0);
    gload16(gB1 + k0, lB1);
    __syncthreads();
    bfrag_t af[4], bb[4];
    #pragma unroll
    for (int mi=0;mi<4;++mi){
      int r = arow + mi*16;
      int uu = g ^ ((r>>1)&3);
      af[mi] = *(const bfrag_t*)((const char*)At + r*64 + uu*16);
    }
    #pragma unroll
    for (int ni=0;ni<4;++ni){
      int r = brow + ni*16;
      int uu = g ^ ((r>>1)&3);
      bb[ni] = *(const bfrag_t*)((const char*)Bt + r*64 + uu*16);
    }
    #pragma unroll
    for (int mi=0;mi<4;++mi)
      #pragma unroll
      for (int ni=0;ni<4;++ni)
        acc[mi][ni] = __builtin_amdgcn_mfma_f32_16x16x32_bf16(af[mi], bb[ni], acc[mi][ni], 0, 0, 0);
    __syncthreads();
  }

  #pragma unroll
  for (int mi=0;mi<4;++mi){
    int tbase = t0 + wr*64 + mi*16 + (lane>>4)*4;
    #pragma unroll
    for (int ni=0;ni<4;++ni){
      int col = bn0 + wc*64 + ni*16 + (lane&15);
      int b = col>>7, n = col&127;
      size_t obase = (size_t)b*(SEQ*NCH) + n;
      #pragma unroll
      for (int r=0;r<4;++r){
        int t = tbase + r;
        if (t<SEQ) out[obase + (size_t)t*NCH] = acc[mi][ni][r] + bias[t];
      }
    }
  }
}

extern "C" void kernel_launch(void* const* d_in, const int* in_sizes, int n_in,
                              void* d_out, int out_size, void* d_ws, size_t ws_size,
                              hipStream_t stream)
{
  const float* x     = (const float*)d_in[0];
  const float* fqWr  = (const float*)d_in[1];
  const float* fqWi  = (const float*)d_in[2];
  const float* fqbr  = (const float*)d_in[3];
  const float* fqbi  = (const float*)d_in[4];
  const float* WPW   = (const float*)d_in[5];
  const float* WPb   = (const float*)d_in[6];
  const float* Wpos  = (const float*)d_in[7];
  const float* m1r   = (const float*)d_in[8];
  const float* m1i   = (const float*)d_in[9];
  const float* m1br  = (const float*)d_in[10];
  const float* m1bi  = (const float*)d_in[11];
  const float* fxr   = (const float*)d_in[12];
  const float* fxi   = (const float*)d_in[13];
  const float* fxbr  = (const float*)d_in[14];
  const float* fxbi  = (const float*)d_in[15];
  const float* pjr   = (const float*)d_in[16];
  const float* pji   = (const float*)d_in[17];
  const float* pjbr  = (const float*)d_in[18];
  const float* pjbi  = (const float*)d_in[19];
  const float* headW = (const float*)d_in[20];
  const float* headb = (const float*)d_in[21];

  char* ws = (char*)d_ws;
  size_t off = 0;
  auto alloc = [&](size_t bytes)->void*{ void* p = ws + off; off += (bytes + 255) & ~(size_t)255; return p; };
  __hip_bfloat16* Abig = (__hip_bfloat16*)alloc((size_t)BN*KP*2);
  __hip_bfloat16* BTm  = (__hip_bfloat16*)alloc((size_t)MT*KP*2);
  float* A1r = (float*)alloc((size_t)DOM*720*4);
  float* A1i = (float*)alloc((size_t)DOM*720*4);
  cf* C   = (cf*)alloc((size_t)FRQ*PER*8);
  cf* PM  = (cf*)alloc((size_t)POUT*PIN*8);
  cf* M2  = (cf*)alloc((size_t)FRQ*FRQ*8);
  cf* o3b = (cf*)alloc((size_t)FRQ*POUT*8);
  float* bias = (float*)alloc((size_t)SEQ*4);

  fused_pre<<<DOM+1+3072+2048,512,0,stream>>>(WPW,WPb, m1r,m1i,m1br,m1bi, fxr,fxi,fxbr,fxbi,
                                              pjr,pji,pjbr,pjbi, fqWr,fqWi, x, Wpos,
                                              C,PM,M2,o3b, A1r,A1i, Abig);
  p_big3<<<SEQ,512,0,stream>>>(headW, PM, M2, o3b, C, fqbr, fqbi, headb, A1r, A1i, BTm, bias);
  gemm_main<<<dim3(128, 6), 256, 0, stream>>>(BTm, Abig, bias, (float*)d_out);
}